// Round 7
// baseline (214.909 us; speedup 1.0000x reference)
//
#include <hip/hip_runtime.h>
#include <hip/hip_bf16.h>

// OutlierAwareLinear: y = x @ W^T + b, then per-token outlier-aware fake-quant.
// M=16384 (B*S), K=2048 (D_in), N=2048 (D_out), all fp32 in/out.
//
// Pipeline:
//   1) k_convert: x,W f32 -> bf16 into d_ws
//   2) k_gemm8: 256x256 8-phase bf16 MFMA GEMM (T2 swizzle + T3/T4 counted
//      vmcnt + T5 setprio); COMPILER fine-grained lgkmcnt (no forced drain)
//      so ds_read completion hides under MFMA issue; vmcnt(4) boundary.
//   3) k_quant: per-token std -> thr -> clamped absmax -> fake-quant, in place

typedef __attribute__((ext_vector_type(8))) short bf16x8;
typedef __attribute__((ext_vector_type(4))) float f32x4;
typedef __attribute__((ext_vector_type(8))) unsigned short u16x8;

#define QMAX_F 127.0f
#define THR_SIG 3.0f
#define EPS_F 1e-6f

__device__ __forceinline__ unsigned short f2bf(float f) {
    unsigned int u = __builtin_bit_cast(unsigned int, f);
    unsigned int r = u + 0x7fffu + ((u >> 16) & 1u);
    return (unsigned short)(r >> 16);
}

__device__ __forceinline__ void gl_lds16(const unsigned short* g, unsigned short* l) {
    __builtin_amdgcn_global_load_lds((const __attribute__((address_space(1))) void*)g,
                                     (__attribute__((address_space(3))) void*)l, 16, 0, 0);
}

__global__ __launch_bounds__(256) void k_convert(const float* __restrict__ in,
                                                 unsigned short* __restrict__ out,
                                                 long long n) {
    long long i = ((long long)blockIdx.x * 256 + threadIdx.x) * 8;
    if (i + 8 <= n) {
        f32x4 a = *(const f32x4*)(in + i);
        f32x4 b = *(const f32x4*)(in + i + 4);
        u16x8 o;
#pragma unroll
        for (int j = 0; j < 4; ++j) { o[j] = f2bf(a[j]); o[4 + j] = f2bf(b[j]); }
        *(u16x8*)(out + i) = o;
    }
}

// ---------------------------------------------------------------------------
// 256x256x64 8-phase GEMM, C = A·B^T + bias. A[M][K], B[N][K] bf16 K-major.
// 512 thr = 8 waves (2M x 4N); per wave 128x64 out = acc[8][4] (16x16x32 MFMA).
// LDS 128 KiB: [buf2][A/B][half2][128][64] bf16 (half-tile = 16 KB = 2 loads).
// Swizzle (T2, both-sides): 16B slot s at row r holds logical slot s^(r&7);
// staging uses linear LDS dest + pre-swizzled per-lane global source.
//
// Per-phase: reads + one half-tile stage; bar; setprio; MFMA cluster; bar.
// NO manual lgkmcnt(0): ds_reads are compiler-visible, SIInsertWaitcnts emits
// minimal per-operand lgkmcnt inside the MFMA cluster -> read tail overlaps
// MFMA issue (this was the r6 serializer: forced full drain = serial
// 375-cyc-read + 620-cyc-MFMA per phase; measured 5500 cyc/tile vs 2500 floor).
// Correctness: every phase-p read feeds a phase-p MFMA, so per-operand waits
// imply all reads complete before the wave's last MFMA -> before barrier-2.
// Stage-overwrite ledger: Ah(t+1)@p1/p2 vs A last read p3(t-1) [>=2 barriers];
// Bh(t+2)@p3/p4 vs B last read p2(t) [>=1 barrier]. Boundary vmcnt(4) retires
// exactly tile t+1's loads; sched_barrier(0) pins reads below data-valid point.
// ---------------------------------------------------------------------------
#define STGA(h, i, tt)                                                              \
    gl_lds16(aSrc + (size_t)((h) * 128 + (i) * 64) * K + (tt) * 64,                 \
             &lds[((tt) & 1) * 32768 + (h) * 8192 + (i) * 4096 + dstW])
#define STGB(h, i, tt)                                                              \
    gl_lds16(bSrc + (size_t)((h) * 128 + (i) * 64) * K + (tt) * 64,                 \
             &lds[((tt) & 1) * 32768 + 16384 + (h) * 8192 + (i) * 4096 + dstW])

__global__ __launch_bounds__(512, 2) void k_gemm8(const unsigned short* __restrict__ A,
                                                  const unsigned short* __restrict__ B,
                                                  const float* __restrict__ bias,
                                                  float* __restrict__ C,
                                                  int M, int N, int K) {
    __shared__ unsigned short lds[65536];  // 128 KiB

    const int nbn = N >> 8;
    const int nwg = gridDim.x;
    int lin = blockIdx.x;
    int swz = lin;
    if ((nwg & 7) == 0) {  // bijective XCD swizzle
        int cpx = nwg >> 3;
        swz = (lin & 7) * cpx + (lin >> 3);
    }
    const int bm = swz / nbn, bn = swz % nbn;
    const int rowBase = bm << 8, colBase = bn << 8;

    const int tid = threadIdx.x;
    const int lane = tid & 63, w = tid >> 6;
    const int wr = w >> 2, wc = w & 3;

    // staging: lane l covers row (base + l>>3), phys slot l&7 -> logical slot
    // (l&7)^(l>>3); global source pre-swizzled accordingly.
    const int lrow = lane >> 3;
    const int lslot = (lane & 7) ^ lrow;
    const unsigned short* aSrc = A + (size_t)(rowBase + w * 8 + lrow) * K + lslot * 8;
    const unsigned short* bSrc = B + (size_t)(colBase + w * 8 + lrow) * K + lslot * 8;
    const int dstW = w * 512;  // (w*8 rows)*64 elems

    // ds_read offsets (elems): row = (16-blk) + fr, phys slot = logical ^ (fr&7)
    const int fr = lane & 15;
    const int ps0 = (((lane >> 4) ^ (lane & 7))) * 8;  // ks=0; ks=1 -> ^32
    const int aO0 = wr * 8192 + fr * 64 + ps0;
    const int aO1 = wr * 8192 + fr * 64 + (ps0 ^ 32);
    const int bO0 = (wc >> 1) * 8192 + ((wc & 1) * 64 + fr) * 64 + ps0;
    const int bO1 = (wc >> 1) * 8192 + ((wc & 1) * 64 + fr) * 64 + (ps0 ^ 32);

    f32x4 acc[8][4];
#pragma unroll
    for (int i = 0; i < 8; ++i)
#pragma unroll
        for (int j = 0; j < 4; ++j) acc[i][j] = (f32x4){0.f, 0.f, 0.f, 0.f};

    const int nt = K >> 6;

    // prologue: tile0 full (8 loads) + Bh0,Bh1(tile1) (4 loads); vmcnt(4)
    // retires tile0 -> resident; tile1's B-halves in flight (induction state).
    STGA(0, 0, 0); STGA(0, 1, 0); STGA(1, 0, 0); STGA(1, 1, 0);
    STGB(0, 0, 0); STGB(0, 1, 0); STGB(1, 0, 0); STGB(1, 1, 0);
    STGB(0, 0, 1); STGB(0, 1, 1); STGB(1, 0, 1); STGB(1, 1, 1);
    asm volatile("s_waitcnt vmcnt(4)" ::: "memory");  // tile0 resident
    __builtin_amdgcn_sched_barrier(0);
    __builtin_amdgcn_s_barrier();

    for (int t = 0; t < nt; ++t) {
        const unsigned short* Ab = lds + (t & 1) * 32768;
        const unsigned short* Bb = Ab + 16384;
        bf16x8 aQ[8], bLo[4], bHi[4];

        // ---- phase 1: read A mi0-3 + B ni0-1; stage Ah0(t+1); MFMA (m0,n0)
#pragma unroll
        for (int mi = 0; mi < 4; ++mi) {
            aQ[2 * mi] = *(const bf16x8*)(Ab + aO0 + mi * 1024);
            aQ[2 * mi + 1] = *(const bf16x8*)(Ab + aO1 + mi * 1024);
        }
#pragma unroll
        for (int ni = 0; ni < 2; ++ni) {
            bLo[2 * ni] = *(const bf16x8*)(Bb + bO0 + ni * 1024);
            bLo[2 * ni + 1] = *(const bf16x8*)(Bb + bO1 + ni * 1024);
        }
        if (t + 1 < nt) { STGA(0, 0, t + 1); STGA(0, 1, t + 1); }
        __builtin_amdgcn_s_barrier();
        __builtin_amdgcn_s_setprio(1);
#pragma unroll
        for (int mi = 0; mi < 4; ++mi)
#pragma unroll
            for (int ni = 0; ni < 2; ++ni) {
                acc[mi][ni] = __builtin_amdgcn_mfma_f32_16x16x32_bf16(
                    aQ[2 * mi], bLo[2 * ni], acc[mi][ni], 0, 0, 0);
                acc[mi][ni] = __builtin_amdgcn_mfma_f32_16x16x32_bf16(
                    aQ[2 * mi + 1], bLo[2 * ni + 1], acc[mi][ni], 0, 0, 0);
            }
        __builtin_amdgcn_s_setprio(0);
        __builtin_amdgcn_sched_barrier(0);
        __builtin_amdgcn_s_barrier();

        // ---- phase 2: read B ni2-3; stage Ah1(t+1); MFMA (m0,n1)
#pragma unroll
        for (int ni = 0; ni < 2; ++ni) {
            bHi[2 * ni] = *(const bf16x8*)(Bb + bO0 + (ni + 2) * 1024);
            bHi[2 * ni + 1] = *(const bf16x8*)(Bb + bO1 + (ni + 2) * 1024);
        }
        if (t + 1 < nt) { STGA(1, 0, t + 1); STGA(1, 1, t + 1); }
        __builtin_amdgcn_s_barrier();
        __builtin_amdgcn_s_setprio(1);
#pragma unroll
        for (int mi = 0; mi < 4; ++mi)
#pragma unroll
            for (int ni = 0; ni < 2; ++ni) {
                acc[mi][2 + ni] = __builtin_amdgcn_mfma_f32_16x16x32_bf16(
                    aQ[2 * mi], bHi[2 * ni], acc[mi][2 + ni], 0, 0, 0);
                acc[mi][2 + ni] = __builtin_amdgcn_mfma_f32_16x16x32_bf16(
                    aQ[2 * mi + 1], bHi[2 * ni + 1], acc[mi][2 + ni], 0, 0, 0);
            }
        __builtin_amdgcn_s_setprio(0);
        __builtin_amdgcn_sched_barrier(0);
        __builtin_amdgcn_s_barrier();

        // ---- phase 3: read A mi4-7; stage Bh0(t+2); MFMA (m1,n1)
        // (buf B-halves last read at p2; end-of-p2 barrier makes this safe)
#pragma unroll
        for (int mi = 0; mi < 4; ++mi) {
            aQ[2 * mi] = *(const bf16x8*)(Ab + aO0 + (mi + 4) * 1024);
            aQ[2 * mi + 1] = *(const bf16x8*)(Ab + aO1 + (mi + 4) * 1024);
        }
        if (t + 2 < nt) { STGB(0, 0, t + 2); STGB(0, 1, t + 2); }
        __builtin_amdgcn_s_barrier();
        __builtin_amdgcn_s_setprio(1);
#pragma unroll
        for (int mi = 0; mi < 4; ++mi)
#pragma unroll
            for (int ni = 0; ni < 2; ++ni) {
                acc[4 + mi][2 + ni] = __builtin_amdgcn_mfma_f32_16x16x32_bf16(
                    aQ[2 * mi], bHi[2 * ni], acc[4 + mi][2 + ni], 0, 0, 0);
                acc[4 + mi][2 + ni] = __builtin_amdgcn_mfma_f32_16x16x32_bf16(
                    aQ[2 * mi + 1], bHi[2 * ni + 1], acc[4 + mi][2 + ni], 0, 0, 0);
            }
        __builtin_amdgcn_s_setprio(0);
        __builtin_amdgcn_sched_barrier(0);
        __builtin_amdgcn_s_barrier();

        // ---- phase 4: stage Bh1(t+2); MFMA (m1,n0); boundary vmcnt(4)
        if (t + 2 < nt) { STGB(1, 0, t + 2); STGB(1, 1, t + 2); }
        __builtin_amdgcn_s_barrier();
        __builtin_amdgcn_s_setprio(1);
#pragma unroll
        for (int mi = 0; mi < 4; ++mi)
#pragma unroll
            for (int ni = 0; ni < 2; ++ni) {
                acc[4 + mi][ni] = __builtin_amdgcn_mfma_f32_16x16x32_bf16(
                    aQ[2 * mi], bLo[2 * ni], acc[4 + mi][ni], 0, 0, 0);
                acc[4 + mi][ni] = __builtin_amdgcn_mfma_f32_16x16x32_bf16(
                    aQ[2 * mi + 1], bLo[2 * ni + 1], acc[4 + mi][ni], 0, 0, 0);
            }
        __builtin_amdgcn_s_setprio(0);
        __builtin_amdgcn_sched_barrier(0);
        if (t < nt - 2) {
            asm volatile("s_waitcnt vmcnt(4)" ::: "memory");  // tile t+1 resident
        } else {
            asm volatile("s_waitcnt vmcnt(0)" ::: "memory");
        }
        __builtin_amdgcn_sched_barrier(0);
        __builtin_amdgcn_s_barrier();
    }

    // epilogue: C/D layout col = lane&15, row = (lane>>4)*4 + r  [m89]
    const int rowoff = (lane >> 4) * 4;
#pragma unroll
    for (int ni = 0; ni < 4; ++ni) {
        int gc = colBase + wc * 64 + ni * 16 + fr;
        float bv = bias[gc];
#pragma unroll
        for (int mi = 0; mi < 8; ++mi) {
            int gr = rowBase + wr * 128 + mi * 16 + rowoff;
#pragma unroll
            for (int r = 0; r < 4; ++r)
                C[(size_t)(gr + r) * N + gc] = acc[mi][ni][r] + bv;
        }
    }
}

// Fallback (no ws): f32 inputs, convert during staging (padded LDS, reg-staged).
__global__ __launch_bounds__(256) void k_gemm_f32(const float* __restrict__ Av,
                                                  const float* __restrict__ Bv,
                                                  const float* __restrict__ bias,
                                                  float* __restrict__ C,
                                                  int M, int N, int K) {
    __shared__ unsigned short sA[128 * 40];
    __shared__ unsigned short sB[128 * 40];

    const int nbn = N / 128;
    const int nwg = gridDim.x;
    int lin = blockIdx.x;
    int swz = lin;
    if ((nwg & 7) == 0) {
        int cpx = nwg >> 3;
        swz = (lin & 7) * cpx + (lin >> 3);
    }
    const int bm = swz / nbn, bn = swz % nbn;
    const int rowBase = bm * 128, colBase = bn * 128;

    const int tid = threadIdx.x;
    const int lane = tid & 63, wave = tid >> 6;
    const int wr = wave >> 1, wc = wave & 1;
    const int fr = lane & 15;
    const int kblk = (lane >> 4) * 8;

    f32x4 acc[4][4];
#pragma unroll
    for (int i = 0; i < 4; ++i)
#pragma unroll
        for (int j = 0; j < 4; ++j) acc[i][j] = (f32x4){0.f, 0.f, 0.f, 0.f};

    const int nk = K / 32;
    for (int kt = 0; kt < nk; ++kt) {
        const int kb = kt * 32;
        __syncthreads();
#pragma unroll
        for (int cc = 0; cc < 2; ++cc) {
            int c = tid + cc * 256;
            int row = c >> 2;
            int k8 = (c & 3) * 8;
            const float* gA = Av + (size_t)(rowBase + row) * K + kb + k8;
            const float* gB = Bv + (size_t)(colBase + row) * K + kb + k8;
            f32x4 a0 = *(const f32x4*)gA, a1 = *(const f32x4*)(gA + 4);
            f32x4 b0 = *(const f32x4*)gB, b1 = *(const f32x4*)(gB + 4);
            u16x8 va, vb;
#pragma unroll
            for (int j = 0; j < 4; ++j) {
                va[j] = f2bf(a0[j]); va[4 + j] = f2bf(a1[j]);
                vb[j] = f2bf(b0[j]); vb[4 + j] = f2bf(b1[j]);
            }
            *(u16x8*)&sA[row * 40 + k8] = va;
            *(u16x8*)&sB[row * 40 + k8] = vb;
        }
        __syncthreads();

        bf16x8 af[4], bfrag[4];
#pragma unroll
        for (int mi = 0; mi < 4; ++mi)
            af[mi] = *(const bf16x8*)&sA[(wr * 64 + mi * 16 + fr) * 40 + kblk];
#pragma unroll
        for (int ni = 0; ni < 4; ++ni)
            bfrag[ni] = *(const bf16x8*)&sB[(wc * 64 + ni * 16 + fr) * 40 + kblk];
#pragma unroll
        for (int mi = 0; mi < 4; ++mi)
#pragma unroll
            for (int ni = 0; ni < 4; ++ni)
                acc[mi][ni] = __builtin_amdgcn_mfma_f32_16x16x32_bf16(
                    af[mi], bfrag[ni], acc[mi][ni], 0, 0, 0);
    }

    const int rowoff = (lane >> 4) * 4;
#pragma unroll
    for (int ni = 0; ni < 4; ++ni) {
        int gc = colBase + wc * 64 + ni * 16 + fr;
        float bv = bias[gc];
#pragma unroll
        for (int mi = 0; mi < 4; ++mi) {
            int gr = rowBase + wr * 64 + mi * 16 + rowoff;
#pragma unroll
            for (int r = 0; r < 4; ++r)
                C[(size_t)(gr + r) * N + gc] = acc[mi][ni][r] + bv;
        }
    }
}

// Per-token outlier-aware fake-quant, in place. One block per row of D=2048.
__global__ __launch_bounds__(256) void k_quant(float* __restrict__ y, int D) {
    float* p = y + (size_t)blockIdx.x * D;
    const int tid = threadIdx.x;
    f32x4 v0 = *(const f32x4*)(p + tid * 8);
    f32x4 v1 = *(const f32x4*)(p + tid * 8 + 4);

    float s = 0.f, ss = 0.f;
#pragma unroll
    for (int j = 0; j < 4; ++j) {
        s += v0[j] + v1[j];
        ss += v0[j] * v0[j] + v1[j] * v1[j];
    }
#pragma unroll
    for (int off = 32; off > 0; off >>= 1) {
        s += __shfl_down(s, off, 64);
        ss += __shfl_down(ss, off, 64);
    }

    __shared__ float rs[4], rss[4], bc[2];
    const int wave = tid >> 6, lane = tid & 63;
    if (lane == 0) { rs[wave] = s; rss[wave] = ss; }
    __syncthreads();
    if (tid == 0) {
        float S = rs[0] + rs[1] + rs[2] + rs[3];
        float SS = rss[0] + rss[1] + rss[2] + rss[3];
        float mean = S / (float)D;
        float var = fmaxf(SS / (float)D - mean * mean, 0.f);
        bc[0] = THR_SIG * sqrtf(var);
    }
    __syncthreads();
    const float thr = bc[0];

    float m = 0.f;
#pragma unroll
    for (int j = 0; j < 4; ++j) {
        m = fmaxf(m, fminf(fabsf(v0[j]), thr));
        m = fmaxf(m, fminf(fabsf(v1[j]), thr));
    }
#pragma unroll
    for (int off = 32; off > 0; off >>= 1) m = fmaxf(m, __shfl_down(m, off, 64));
    if (lane == 0) rs[wave] = m;
    __syncthreads();
    if (tid == 0) {
        float mm = fmaxf(fmaxf(rs[0], rs[1]), fmaxf(rs[2], rs[3]));
        bc[1] = fmaxf(mm / QMAX_F, EPS_F);
    }
    __syncthreads();
    const float scale = bc[1];

#pragma unroll
    for (int j = 0; j < 4; ++j) {
        {
            float v = v0[j];
            float c = fminf(fmaxf(v, -thr), thr);
            float q = rintf(c / scale) * scale;
            v0[j] = (fabsf(v) > thr) ? v : q;
        }
        {
            float v = v1[j];
            float c = fminf(fmaxf(v, -thr), thr);
            float q = rintf(c / scale) * scale;
            v1[j] = (fabsf(v) > thr) ? v : q;
        }
    }
    *(f32x4*)(p + tid * 8) = v0;
    *(f32x4*)(p + tid * 8 + 4) = v1;
}

extern "C" void kernel_launch(void* const* d_in, const int* in_sizes, int n_in,
                              void* d_out, int out_size, void* d_ws, size_t ws_size,
                              hipStream_t stream) {
    const float* x = (const float*)d_in[0];
    const float* W = (const float*)d_in[1];
    const float* b = (const float*)d_in[2];
    float* out = (float*)d_out;

    const int Dout = in_sizes[2];
    const int Din = in_sizes[1] / Dout;
    const int M = in_sizes[0] / Din;

    const size_t nA = (size_t)M * Din;
    const size_t nB = (size_t)Dout * Din;
    const size_t need = (nA + nB) * sizeof(unsigned short);
    const bool fits8 = (M % 256 == 0) && (Dout % 256 == 0) && (Din % 64 == 0) && (Din >= 256);
    const bool pre = (ws_size >= need) && fits8;

    if (pre) {
        unsigned short* xb = (unsigned short*)d_ws;
        unsigned short* wb = xb + nA;
        int gA = (int)((nA + 8 * 256 - 1) / (8 * 256));
        int gB = (int)((nB + 8 * 256 - 1) / (8 * 256));
        k_convert<<<gA, 256, 0, stream>>>(x, xb, (long long)nA);
        k_convert<<<gB, 256, 0, stream>>>(W, wb, (long long)nB);
        int gridGemm = (M / 256) * (Dout / 256);
        k_gemm8<<<gridGemm, 512, 0, stream>>>(xb, wb, b, out, M, Dout, Din);
    } else {
        int gridGemm = (M / 128) * (Dout / 128);
        k_gemm_f32<<<gridGemm, 256, 0, stream>>>(x, W, b, out, M, Dout, Din);
    }
    k_quant<<<M, 256, 0, stream>>>(out, Dout);
}

// Round 8
// 214.826 us; speedup vs baseline: 1.0004x; 1.0004x over previous
//
#include <hip/hip_runtime.h>
#include <hip/hip_bf16.h>

// OutlierAwareLinear: y = x @ W^T + b, then per-token outlier-aware fake-quant.
// M=16384 (B*S), K=2048 (D_in), N=2048 (D_out), all fp32 in/out.
//
// Pipeline:
//   1) k_convert: x,W f32 -> bf16 into d_ws
//   2) k_gemm4: 256x256x64 bf16 MFMA GEMM, 4 waves x 128x128-per-wave
//      (HALVES LDS read traffic vs 8x(128x64): 128KB vs 192KB per K-tile;
//      kernel is LDS-read-bound: floor 1536 cyc LDS + 620 MFMA per tile).
//      T2 swizzle + counted vmcnt + setprio, bias fused.
//   3) k_quant: per-token std -> thr -> clamped absmax -> fake-quant, in place

typedef __attribute__((ext_vector_type(8))) short bf16x8;
typedef __attribute__((ext_vector_type(4))) float f32x4;
typedef __attribute__((ext_vector_type(8))) unsigned short u16x8;

#define QMAX_F 127.0f
#define THR_SIG 3.0f
#define EPS_F 1e-6f

__device__ __forceinline__ unsigned short f2bf(float f) {
    unsigned int u = __builtin_bit_cast(unsigned int, f);
    unsigned int r = u + 0x7fffu + ((u >> 16) & 1u);
    return (unsigned short)(r >> 16);
}

__device__ __forceinline__ void gl_lds16(const unsigned short* g, unsigned short* l) {
    __builtin_amdgcn_global_load_lds((const __attribute__((address_space(1))) void*)g,
                                     (__attribute__((address_space(3))) void*)l, 16, 0, 0);
}

__global__ __launch_bounds__(256) void k_convert(const float* __restrict__ in,
                                                 unsigned short* __restrict__ out,
                                                 long long n) {
    long long i = ((long long)blockIdx.x * 256 + threadIdx.x) * 8;
    if (i + 8 <= n) {
        f32x4 a = *(const f32x4*)(in + i);
        f32x4 b = *(const f32x4*)(in + i + 4);
        u16x8 o;
#pragma unroll
        for (int j = 0; j < 4; ++j) { o[j] = f2bf(a[j]); o[4 + j] = f2bf(b[j]); }
        *(u16x8*)(out + i) = o;
    }
}

// ---------------------------------------------------------------------------
// 256x256x64 GEMM, C = A·B^T + bias. A[M][K], B[N][K] bf16 K-major.
// 256 thr = 4 waves (2M x 2N); per wave 128x128 out = acc[8][8] (16x16x32).
// LDS 128 KiB: [buf2][A/B][half2][128][64] bf16. Wave (wr,wc) reads ONLY
// A-half wr and B-half wc -> total LDS reads = 4 x 32KB = 128KB/K-tile
// (vs 192KB for 8x(128x64)) -- the dominant term, since LDS pipe (85 B/cyc)
// is the bottleneck resource.
// Swizzle (T2): 16B slot s at row r holds logical slot s^(r&7); staging uses
// linear LDS dest + pre-swizzled per-lane global source.
//
// Phases per K-tile t (reads ||  one half-tile stage per phase, m196 style):
//   p1: read Alo(mi0-3)+Blo(ni0-3) [16]; stage Ah0(t+1); bar; MFMA (m0,n0)
//   p2: read Bhi(ni4-7) [8];             stage Ah1(t+1); bar; MFMA (m0,n1)
//   p3: read Ahi(mi4-7) [8];             stage Bh0(t+2); bar; MFMA (m1,n1)
//   p4:                                  stage Bh1(t+2); bar; MFMA (m1,n0)
//   boundary: vmcnt(8); bar      (stage call = 4KB; half-tile = 4 calls)
// Ledger: A-halves last read p3, staged for t+1 at p1/p2 (>=2 barriers after
// p3(t-1)); B-halves last read p2, staged for t+2 at p3/p4 (>=1 barrier).
// Boundary: issued during t = Ah(t+1) 8 + Bh(t+2) 8; carry = Bh(t+1) 8;
// vmcnt(8) retires tile t+1's 16 calls, leaves Bh(t+2)'s 8 in flight.
// Prologue: tile0 (16 calls) + Bh0,Bh1(tile1) (8); vmcnt(8) -> tile0 resident.
// MFMA clusters iterate ks OUTER: 16 independent MFMA per pass (no dependent
// back-to-back acc chains -- required at 1 wave/SIMD).
// VGPR: 256 acc + <=96 operands + misc ~ 380 < 450 no-spill [m08]; 1 wave/SIMD.
// ---------------------------------------------------------------------------
#define STGA(h, i, tt)                                                              \
    gl_lds16(aSrc + (size_t)((h) * 128 + (i) * 32) * K + (tt) * 64,                 \
             &lds[((tt) & 1) * 32768 + (h) * 8192 + (i) * 2048 + dstW])
#define STGB(h, i, tt)                                                              \
    gl_lds16(bSrc + (size_t)((h) * 128 + (i) * 32) * K + (tt) * 64,                 \
             &lds[((tt) & 1) * 32768 + 16384 + (h) * 8192 + (i) * 2048 + dstW])

__global__ __launch_bounds__(256, 1) void k_gemm4(const unsigned short* __restrict__ A,
                                                  const unsigned short* __restrict__ B,
                                                  const float* __restrict__ bias,
                                                  float* __restrict__ C,
                                                  int M, int N, int K) {
    __shared__ unsigned short lds[65536];  // 128 KiB

    const int nbn = N >> 8;
    const int nwg = gridDim.x;
    int lin = blockIdx.x;
    int swz = lin;
    if ((nwg & 7) == 0) {  // bijective XCD swizzle
        int cpx = nwg >> 3;
        swz = (lin & 7) * cpx + (lin >> 3);
    }
    const int bm = swz / nbn, bn = swz % nbn;
    const int rowBase = bm << 8, colBase = bn << 8;

    const int tid = threadIdx.x;
    const int lane = tid & 63, w = tid >> 6;
    const int wr = w >> 1, wc = w & 1;

    // staging: lane l covers row (base + l>>3), phys slot l&7 -> logical slot
    // (l&7)^(l>>3); global source pre-swizzled. 4 waves x 8 rows = 32 rows/call.
    const int lrow = lane >> 3;
    const int lslot = (lane & 7) ^ lrow;
    const unsigned short* aSrc = A + (size_t)(rowBase + w * 8 + lrow) * K + lslot * 8;
    const unsigned short* bSrc = B + (size_t)(colBase + w * 8 + lrow) * K + lslot * 8;
    const int dstW = w * 512;  // (w*8 rows)*64 elems

    // ds_read offsets (elems): wave reads its OWN half: A half wr, B half wc.
    // row = mi*16 + fr (mi 0..7), phys slot = logical ^ (fr&7).
    const int fr = lane & 15;
    const int ps0 = (((lane >> 4) ^ (lane & 7))) * 8;  // ks=0; ks=1 -> ^32
    const int aO0 = wr * 8192 + fr * 64 + ps0;
    const int aO1 = wr * 8192 + fr * 64 + (ps0 ^ 32);
    const int bO0 = wc * 8192 + fr * 64 + ps0;
    const int bO1 = wc * 8192 + fr * 64 + (ps0 ^ 32);

    f32x4 acc[8][8];
#pragma unroll
    for (int i = 0; i < 8; ++i)
#pragma unroll
        for (int j = 0; j < 8; ++j) acc[i][j] = (f32x4){0.f, 0.f, 0.f, 0.f};

    const int nt = K >> 6;

    // prologue: tile0 full (16 calls) + Bh0,Bh1(tile1) (8 calls); vmcnt(8).
#pragma unroll
    for (int i = 0; i < 4; ++i) { STGA(0, i, 0); STGA(1, i, 0); }
#pragma unroll
    for (int i = 0; i < 4; ++i) { STGB(0, i, 0); STGB(1, i, 0); }
#pragma unroll
    for (int i = 0; i < 4; ++i) { STGB(0, i, 1); STGB(1, i, 1); }
    asm volatile("s_waitcnt vmcnt(8)" ::: "memory");  // tile0 resident
    __builtin_amdgcn_sched_barrier(0);
    __builtin_amdgcn_s_barrier();

    for (int t = 0; t < nt; ++t) {
        const unsigned short* Ab = lds + (t & 1) * 32768;
        const unsigned short* Bb = Ab + 16384;
        bf16x8 aLo[8], aHi[8], bLo[8], bHi[8];

        // ---- phase 1: read A lo-half + B lo-half; stage Ah0(t+1); MFMA (m0,n0)
#pragma unroll
        for (int mi = 0; mi < 4; ++mi) {
            aLo[2 * mi] = *(const bf16x8*)(Ab + aO0 + mi * 1024);
            aLo[2 * mi + 1] = *(const bf16x8*)(Ab + aO1 + mi * 1024);
        }
#pragma unroll
        for (int ni = 0; ni < 4; ++ni) {
            bLo[2 * ni] = *(const bf16x8*)(Bb + bO0 + ni * 1024);
            bLo[2 * ni + 1] = *(const bf16x8*)(Bb + bO1 + ni * 1024);
        }
        if (t + 1 < nt) {
#pragma unroll
            for (int i = 0; i < 4; ++i) STGA(0, i, t + 1);
        }
        __builtin_amdgcn_s_barrier();
        __builtin_amdgcn_s_setprio(1);
#pragma unroll
        for (int ks = 0; ks < 2; ++ks)
#pragma unroll
            for (int mi = 0; mi < 4; ++mi)
#pragma unroll
                for (int ni = 0; ni < 4; ++ni)
                    acc[mi][ni] = __builtin_amdgcn_mfma_f32_16x16x32_bf16(
                        aLo[2 * mi + ks], bLo[2 * ni + ks], acc[mi][ni], 0, 0, 0);
        __builtin_amdgcn_s_setprio(0);
        __builtin_amdgcn_sched_barrier(0);
        __builtin_amdgcn_s_barrier();

        // ---- phase 2: read B hi-half; stage Ah1(t+1); MFMA (m0,n1)
#pragma unroll
        for (int ni = 0; ni < 4; ++ni) {
            bHi[2 * ni] = *(const bf16x8*)(Bb + bO0 + (ni + 4) * 1024);
            bHi[2 * ni + 1] = *(const bf16x8*)(Bb + bO1 + (ni + 4) * 1024);
        }
        if (t + 1 < nt) {
#pragma unroll
            for (int i = 0; i < 4; ++i) STGA(1, i, t + 1);
        }
        __builtin_amdgcn_s_barrier();
        __builtin_amdgcn_s_setprio(1);
#pragma unroll
        for (int ks = 0; ks < 2; ++ks)
#pragma unroll
            for (int mi = 0; mi < 4; ++mi)
#pragma unroll
                for (int ni = 0; ni < 4; ++ni)
                    acc[mi][4 + ni] = __builtin_amdgcn_mfma_f32_16x16x32_bf16(
                        aLo[2 * mi + ks], bHi[2 * ni + ks], acc[mi][4 + ni], 0, 0, 0);
        __builtin_amdgcn_s_setprio(0);
        __builtin_amdgcn_sched_barrier(0);
        __builtin_amdgcn_s_barrier();

        // ---- phase 3: read A hi-half; stage Bh0(t+2); MFMA (m1,n1)
        // (B-halves last read at p2; end-of-p2 barrier makes this safe)
#pragma unroll
        for (int mi = 0; mi < 4; ++mi) {
            aHi[2 * mi] = *(const bf16x8*)(Ab + aO0 + (mi + 4) * 1024);
            aHi[2 * mi + 1] = *(const bf16x8*)(Ab + aO1 + (mi + 4) * 1024);
        }
        if (t + 2 < nt) {
#pragma unroll
            for (int i = 0; i < 4; ++i) STGB(0, i, t + 2);
        }
        __builtin_amdgcn_s_barrier();
        __builtin_amdgcn_s_setprio(1);
#pragma unroll
        for (int ks = 0; ks < 2; ++ks)
#pragma unroll
            for (int mi = 0; mi < 4; ++mi)
#pragma unroll
                for (int ni = 0; ni < 4; ++ni)
                    acc[4 + mi][4 + ni] = __builtin_amdgcn_mfma_f32_16x16x32_bf16(
                        aHi[2 * mi + ks], bHi[2 * ni + ks], acc[4 + mi][4 + ni], 0, 0, 0);
        __builtin_amdgcn_s_setprio(0);
        __builtin_amdgcn_sched_barrier(0);
        __builtin_amdgcn_s_barrier();

        // ---- phase 4: stage Bh1(t+2); MFMA (m1,n0); boundary vmcnt(8)
        if (t + 2 < nt) {
#pragma unroll
            for (int i = 0; i < 4; ++i) STGB(1, i, t + 2);
        }
        __builtin_amdgcn_s_barrier();
        __builtin_amdgcn_s_setprio(1);
#pragma unroll
        for (int ks = 0; ks < 2; ++ks)
#pragma unroll
            for (int mi = 0; mi < 4; ++mi)
#pragma unroll
                for (int ni = 0; ni < 4; ++ni)
                    acc[4 + mi][ni] = __builtin_amdgcn_mfma_f32_16x16x32_bf16(
                        aHi[2 * mi + ks], bLo[2 * ni + ks], acc[4 + mi][ni], 0, 0, 0);
        __builtin_amdgcn_s_setprio(0);
        __builtin_amdgcn_sched_barrier(0);
        if (t < nt - 2) {
            asm volatile("s_waitcnt vmcnt(8)" ::: "memory");  // tile t+1 resident
        } else {
            asm volatile("s_waitcnt vmcnt(0)" ::: "memory");
        }
        __builtin_amdgcn_sched_barrier(0);
        __builtin_amdgcn_s_barrier();
    }

    // epilogue: C/D layout col = lane&15, row = (lane>>4)*4 + r  [m89]
    const int rowoff = (lane >> 4) * 4;
#pragma unroll
    for (int ni = 0; ni < 8; ++ni) {
        int gc = colBase + wc * 128 + ni * 16 + fr;
        float bv = bias[gc];
#pragma unroll
        for (int mi = 0; mi < 8; ++mi) {
            int gr = rowBase + wr * 128 + mi * 16 + rowoff;
#pragma unroll
            for (int r = 0; r < 4; ++r)
                C[(size_t)(gr + r) * N + gc] = acc[mi][ni][r] + bv;
        }
    }
}

// Fallback (no ws): f32 inputs, convert during staging (padded LDS, reg-staged).
__global__ __launch_bounds__(256) void k_gemm_f32(const float* __restrict__ Av,
                                                  const float* __restrict__ Bv,
                                                  const float* __restrict__ bias,
                                                  float* __restrict__ C,
                                                  int M, int N, int K) {
    __shared__ unsigned short sA[128 * 40];
    __shared__ unsigned short sB[128 * 40];

    const int nbn = N / 128;
    const int nwg = gridDim.x;
    int lin = blockIdx.x;
    int swz = lin;
    if ((nwg & 7) == 0) {
        int cpx = nwg >> 3;
        swz = (lin & 7) * cpx + (lin >> 3);
    }
    const int bm = swz / nbn, bn = swz % nbn;
    const int rowBase = bm * 128, colBase = bn * 128;

    const int tid = threadIdx.x;
    const int lane = tid & 63, wave = tid >> 6;
    const int wr = wave >> 1, wc = wave & 1;
    const int fr = lane & 15;
    const int kblk = (lane >> 4) * 8;

    f32x4 acc[4][4];
#pragma unroll
    for (int i = 0; i < 4; ++i)
#pragma unroll
        for (int j = 0; j < 4; ++j) acc[i][j] = (f32x4){0.f, 0.f, 0.f, 0.f};

    const int nk = K / 32;
    for (int kt = 0; kt < nk; ++kt) {
        const int kb = kt * 32;
        __syncthreads();
#pragma unroll
        for (int cc = 0; cc < 2; ++cc) {
            int c = tid + cc * 256;
            int row = c >> 2;
            int k8 = (c & 3) * 8;
            const float* gA = Av + (size_t)(rowBase + row) * K + kb + k8;
            const float* gB = Bv + (size_t)(colBase + row) * K + kb + k8;
            f32x4 a0 = *(const f32x4*)gA, a1 = *(const f32x4*)(gA + 4);
            f32x4 b0 = *(const f32x4*)gB, b1 = *(const f32x4*)(gB + 4);
            u16x8 va, vb;
#pragma unroll
            for (int j = 0; j < 4; ++j) {
                va[j] = f2bf(a0[j]); va[4 + j] = f2bf(a1[j]);
                vb[j] = f2bf(b0[j]); vb[4 + j] = f2bf(b1[j]);
            }
            *(u16x8*)&sA[row * 40 + k8] = va;
            *(u16x8*)&sB[row * 40 + k8] = vb;
        }
        __syncthreads();

        bf16x8 af[4], bfrag[4];
#pragma unroll
        for (int mi = 0; mi < 4; ++mi)
            af[mi] = *(const bf16x8*)&sA[(wr * 64 + mi * 16 + fr) * 40 + kblk];
#pragma unroll
        for (int ni = 0; ni < 4; ++ni)
            bfrag[ni] = *(const bf16x8*)&sB[(wc * 64 + ni * 16 + fr) * 40 + kblk];
#pragma unroll
        for (int mi = 0; mi < 4; ++mi)
#pragma unroll
            for (int ni = 0; ni < 4; ++ni)
                acc[mi][ni] = __builtin_amdgcn_mfma_f32_16x16x32_bf16(
                    af[mi], bfrag[ni], acc[mi][ni], 0, 0, 0);
    }

    const int rowoff = (lane >> 4) * 4;
#pragma unroll
    for (int ni = 0; ni < 4; ++ni) {
        int gc = colBase + wc * 64 + ni * 16 + fr;
        float bv = bias[gc];
#pragma unroll
        for (int mi = 0; mi < 4; ++mi) {
            int gr = rowBase + wr * 64 + mi * 16 + rowoff;
#pragma unroll
            for (int r = 0; r < 4; ++r)
                C[(size_t)(gr + r) * N + gc] = acc[mi][ni][r] + bv;
        }
    }
}

// Per-token outlier-aware fake-quant, in place. One block per row of D=2048.
__global__ __launch_bounds__(256) void k_quant(float* __restrict__ y, int D) {
    float* p = y + (size_t)blockIdx.x * D;
    const int tid = threadIdx.x;
    f32x4 v0 = *(const f32x4*)(p + tid * 8);
    f32x4 v1 = *(const f32x4*)(p + tid * 8 + 4);

    float s = 0.f, ss = 0.f;
#pragma unroll
    for (int j = 0; j < 4; ++j) {
        s += v0[j] + v1[j];
        ss += v0[j] * v0[j] + v1[j] * v1[j];
    }
#pragma unroll
    for (int off = 32; off > 0; off >>= 1) {
        s += __shfl_down(s, off, 64);
        ss += __shfl_down(ss, off, 64);
    }

    __shared__ float rs[4], rss[4], bc[2];
    const int wave = tid >> 6, lane = tid & 63;
    if (lane == 0) { rs[wave] = s; rss[wave] = ss; }
    __syncthreads();
    if (tid == 0) {
        float S = rs[0] + rs[1] + rs[2] + rs[3];
        float SS = rss[0] + rss[1] + rss[2] + rss[3];
        float mean = S / (float)D;
        float var = fmaxf(SS / (float)D - mean * mean, 0.f);
        bc[0] = THR_SIG * sqrtf(var);
    }
    __syncthreads();
    const float thr = bc[0];

    float m = 0.f;
#pragma unroll
    for (int j = 0; j < 4; ++j) {
        m = fmaxf(m, fminf(fabsf(v0[j]), thr));
        m = fmaxf(m, fminf(fabsf(v1[j]), thr));
    }
#pragma unroll
    for (int off = 32; off > 0; off >>= 1) m = fmaxf(m, __shfl_down(m, off, 64));
    if (lane == 0) rs[wave] = m;
    __syncthreads();
    if (tid == 0) {
        float mm = fmaxf(fmaxf(rs[0], rs[1]), fmaxf(rs[2], rs[3]));
        bc[1] = fmaxf(mm / QMAX_F, EPS_F);
    }
    __syncthreads();
    const float scale = bc[1];

#pragma unroll
    for (int j = 0; j < 4; ++j) {
        {
            float v = v0[j];
            float c = fminf(fmaxf(v, -thr), thr);
            float q = rintf(c / scale) * scale;
            v0[j] = (fabsf(v) > thr) ? v : q;
        }
        {
            float v = v1[j];
            float c = fminf(fmaxf(v, -thr), thr);
            float q = rintf(c / scale) * scale;
            v1[j] = (fabsf(v) > thr) ? v : q;
        }
    }
    *(f32x4*)(p + tid * 8) = v0;
    *(f32x4*)(p + tid * 8 + 4) = v1;
}

extern "C" void kernel_launch(void* const* d_in, const int* in_sizes, int n_in,
                              void* d_out, int out_size, void* d_ws, size_t ws_size,
                              hipStream_t stream) {
    const float* x = (const float*)d_in[0];
    const float* W = (const float*)d_in[1];
    const float* b = (const float*)d_in[2];
    float* out = (float*)d_out;

    const int Dout = in_sizes[2];
    const int Din = in_sizes[1] / Dout;
    const int M = in_sizes[0] / Din;

    const size_t nA = (size_t)M * Din;
    const size_t nB = (size_t)Dout * Din;
    const size_t need = (nA + nB) * sizeof(unsigned short);
    const bool fits8 = (M % 256 == 0) && (Dout % 256 == 0) && (Din % 64 == 0) && (Din >= 256);
    const bool pre = (ws_size >= need) && fits8;

    if (pre) {
        unsigned short* xb = (unsigned short*)d_ws;
        unsigned short* wb = xb + nA;
        int gA = (int)((nA + 8 * 256 - 1) / (8 * 256));
        int gB = (int)((nB + 8 * 256 - 1) / (8 * 256));
        k_convert<<<gA, 256, 0, stream>>>(x, xb, (long long)nA);
        k_convert<<<gB, 256, 0, stream>>>(W, wb, (long long)nB);
        int gridGemm = (M / 256) * (Dout / 256);
        k_gemm4<<<gridGemm, 256, 0, stream>>>(xb, wb, b, out, M, Dout, Din);
    } else {
        int gridGemm = (M / 128) * (Dout / 128);
        k_gemm_f32<<<gridGemm, 256, 0, stream>>>(x, W, b, out, M, Dout, Din);
    }
    k_quant<<<M, 256, 0, stream>>>(out, Dout);
}

// Round 9
// 206.048 us; speedup vs baseline: 1.0430x; 1.0426x over previous
//
#include <hip/hip_runtime.h>
#include <hip/hip_bf16.h>

// OutlierAwareLinear: y = x @ W^T + b, then per-token outlier-aware fake-quant.
// M=16384 (B*S), K=2048 (D_in), N=2048 (D_out), all fp32 in/out.
//
// Pipeline:
//   1) k_convert: x,W f32 -> bf16 into d_ws
//   2) k_gemm8: 256x256x64 bf16 MFMA GEMM, 8 waves, ONE barrier per phase
//      (r9: removed pre-MFMA barrier -> waves de-synchronize within a phase,
//      cross-wave MFMA || ds_read overlap; 4 barriers/tile instead of 8).
//   3) k_quant: per-token std -> thr -> clamped absmax -> fake-quant, in place

typedef __attribute__((ext_vector_type(8))) short bf16x8;
typedef __attribute__((ext_vector_type(4))) float f32x4;
typedef __attribute__((ext_vector_type(8))) unsigned short u16x8;

#define QMAX_F 127.0f
#define THR_SIG 3.0f
#define EPS_F 1e-6f

__device__ __forceinline__ unsigned short f2bf(float f) {
    unsigned int u = __builtin_bit_cast(unsigned int, f);
    unsigned int r = u + 0x7fffu + ((u >> 16) & 1u);
    return (unsigned short)(r >> 16);
}

__device__ __forceinline__ void gl_lds16(const unsigned short* g, unsigned short* l) {
    __builtin_amdgcn_global_load_lds((const __attribute__((address_space(1))) void*)g,
                                     (__attribute__((address_space(3))) void*)l, 16, 0, 0);
}

__global__ __launch_bounds__(256) void k_convert(const float* __restrict__ in,
                                                 unsigned short* __restrict__ out,
                                                 long long n) {
    long long i = ((long long)blockIdx.x * 256 + threadIdx.x) * 8;
    if (i + 8 <= n) {
        f32x4 a = *(const f32x4*)(in + i);
        f32x4 b = *(const f32x4*)(in + i + 4);
        u16x8 o;
#pragma unroll
        for (int j = 0; j < 4; ++j) { o[j] = f2bf(a[j]); o[4 + j] = f2bf(b[j]); }
        *(u16x8*)(out + i) = o;
    }
}

// ---------------------------------------------------------------------------
// 256x256x64 GEMM, C = A·B^T + bias. A[M][K], B[N][K] bf16 K-major.
// 512 thr = 8 waves (2M x 4N); per wave 128x64 out = acc[8][4] (16x16x32).
// LDS 128 KiB: [buf2][A/B][half2][128][64] bf16. T2 swizzle (slot^(row&7)),
// staging = linear LDS dest + pre-swizzled per-lane global source.
//
// ONE-BARRIER-PER-PHASE schedule (r9). Per K-tile t:
//   p1: read A(mi0-3)+B(ni0-1); stage Ah0(t+1); MFMA (m0,n0); bar
//   p2: read B(ni2-3);          stage Ah1(t+1); MFMA (m0,n1); bar
//   p3: read A(mi4-7);          stage Bh0(t+2); MFMA (m1,n1); bar
//   p4:                         stage Bh1(t+2); MFMA (m1,n0); vmcnt(4); bar
// Hazard ledger (all write-after-read edges keep >=1 END-phase barrier):
//   Ah0(t+1)@p1 -> A-half0 of buf[t^1] last read p3(t-1): 2 barriers.
//   Ah1(t+1)@p2 -> A-half1 of buf[t^1] last read p3(t-1): 3 barriers.
//   Bh0(t+2)@p3 -> B-half0 of buf[t]   last read p2(t):   1 barrier (end-p2).
//   Bh1(t+2)@p4 -> B-half1 of buf[t]   last read p2(t):   2 barriers.
// Within-phase: stage targets disjoint from the phase's read regions; a wave's
// own reads retire before its MFMAs (compiler lgkm waits) hence before its
// barrier arrival. Boundary vmcnt(4) is per-wave (own loads) BEFORE the
// barrier; barrier then publishes all waves' staging -> tile t+1 resident.
// Prologue: tile0 full (8 calls) + Bh0,Bh1(tile1) (4); vmcnt(4).
// ---------------------------------------------------------------------------
#define STGA(h, i, tt)                                                              \
    gl_lds16(aSrc + (size_t)((h) * 128 + (i) * 64) * K + (tt) * 64,                 \
             &lds[((tt) & 1) * 32768 + (h) * 8192 + (i) * 4096 + dstW])
#define STGB(h, i, tt)                                                              \
    gl_lds16(bSrc + (size_t)((h) * 128 + (i) * 64) * K + (tt) * 64,                 \
             &lds[((tt) & 1) * 32768 + 16384 + (h) * 8192 + (i) * 4096 + dstW])

__global__ __launch_bounds__(512, 2) void k_gemm8(const unsigned short* __restrict__ A,
                                                  const unsigned short* __restrict__ B,
                                                  const float* __restrict__ bias,
                                                  float* __restrict__ C,
                                                  int M, int N, int K) {
    __shared__ unsigned short lds[65536];  // 128 KiB

    const int nbn = N >> 8;
    const int nwg = gridDim.x;
    int lin = blockIdx.x;
    int swz = lin;
    if ((nwg & 7) == 0) {  // bijective XCD swizzle
        int cpx = nwg >> 3;
        swz = (lin & 7) * cpx + (lin >> 3);
    }
    const int bm = swz / nbn, bn = swz % nbn;
    const int rowBase = bm << 8, colBase = bn << 8;

    const int tid = threadIdx.x;
    const int lane = tid & 63, w = tid >> 6;
    const int wr = w >> 2, wc = w & 3;

    // staging: lane l covers row (base + l>>3), phys slot l&7 -> logical slot
    // (l&7)^(l>>3); global source pre-swizzled accordingly.
    const int lrow = lane >> 3;
    const int lslot = (lane & 7) ^ lrow;
    const unsigned short* aSrc = A + (size_t)(rowBase + w * 8 + lrow) * K + lslot * 8;
    const unsigned short* bSrc = B + (size_t)(colBase + w * 8 + lrow) * K + lslot * 8;
    const int dstW = w * 512;  // (w*8 rows)*64 elems

    // ds_read offsets (elems): row = (16-blk) + fr, phys slot = logical ^ (fr&7)
    const int fr = lane & 15;
    const int ps0 = (((lane >> 4) ^ (lane & 7))) * 8;  // ks=0; ks=1 -> ^32
    const int aO0 = wr * 8192 + fr * 64 + ps0;
    const int aO1 = wr * 8192 + fr * 64 + (ps0 ^ 32);
    const int bO0 = (wc >> 1) * 8192 + ((wc & 1) * 64 + fr) * 64 + ps0;
    const int bO1 = (wc >> 1) * 8192 + ((wc & 1) * 64 + fr) * 64 + (ps0 ^ 32);

    f32x4 acc[8][4];
#pragma unroll
    for (int i = 0; i < 8; ++i)
#pragma unroll
        for (int j = 0; j < 4; ++j) acc[i][j] = (f32x4){0.f, 0.f, 0.f, 0.f};

    const int nt = K >> 6;

    // prologue: tile0 full (8 loads) + Bh0,Bh1(tile1) (4 loads); vmcnt(4).
    STGA(0, 0, 0); STGA(0, 1, 0); STGA(1, 0, 0); STGA(1, 1, 0);
    STGB(0, 0, 0); STGB(0, 1, 0); STGB(1, 0, 0); STGB(1, 1, 0);
    STGB(0, 0, 1); STGB(0, 1, 1); STGB(1, 0, 1); STGB(1, 1, 1);
    asm volatile("s_waitcnt vmcnt(4)" ::: "memory");  // tile0 resident
    __builtin_amdgcn_sched_barrier(0);
    __builtin_amdgcn_s_barrier();

    for (int t = 0; t < nt; ++t) {
        const unsigned short* Ab = lds + (t & 1) * 32768;
        const unsigned short* Bb = Ab + 16384;
        bf16x8 aQ[8], bLo[4], bHi[4];

        // ---- phase 1: read A mi0-3 + B ni0-1; stage Ah0(t+1); MFMA (m0,n0); bar
#pragma unroll
        for (int mi = 0; mi < 4; ++mi) {
            aQ[2 * mi] = *(const bf16x8*)(Ab + aO0 + mi * 1024);
            aQ[2 * mi + 1] = *(const bf16x8*)(Ab + aO1 + mi * 1024);
        }
#pragma unroll
        for (int ni = 0; ni < 2; ++ni) {
            bLo[2 * ni] = *(const bf16x8*)(Bb + bO0 + ni * 1024);
            bLo[2 * ni + 1] = *(const bf16x8*)(Bb + bO1 + ni * 1024);
        }
        if (t + 1 < nt) { STGA(0, 0, t + 1); STGA(0, 1, t + 1); }
        __builtin_amdgcn_s_setprio(1);
#pragma unroll
        for (int mi = 0; mi < 4; ++mi)
#pragma unroll
            for (int ni = 0; ni < 2; ++ni) {
                acc[mi][ni] = __builtin_amdgcn_mfma_f32_16x16x32_bf16(
                    aQ[2 * mi], bLo[2 * ni], acc[mi][ni], 0, 0, 0);
                acc[mi][ni] = __builtin_amdgcn_mfma_f32_16x16x32_bf16(
                    aQ[2 * mi + 1], bLo[2 * ni + 1], acc[mi][ni], 0, 0, 0);
            }
        __builtin_amdgcn_s_setprio(0);
        __builtin_amdgcn_sched_barrier(0);
        __builtin_amdgcn_s_barrier();

        // ---- phase 2: read B ni2-3; stage Ah1(t+1); MFMA (m0,n1); bar
#pragma unroll
        for (int ni = 0; ni < 2; ++ni) {
            bHi[2 * ni] = *(const bf16x8*)(Bb + bO0 + (ni + 2) * 1024);
            bHi[2 * ni + 1] = *(const bf16x8*)(Bb + bO1 + (ni + 2) * 1024);
        }
        if (t + 1 < nt) { STGA(1, 0, t + 1); STGA(1, 1, t + 1); }
        __builtin_amdgcn_s_setprio(1);
#pragma unroll
        for (int mi = 0; mi < 4; ++mi)
#pragma unroll
            for (int ni = 0; ni < 2; ++ni) {
                acc[mi][2 + ni] = __builtin_amdgcn_mfma_f32_16x16x32_bf16(
                    aQ[2 * mi], bHi[2 * ni], acc[mi][2 + ni], 0, 0, 0);
                acc[mi][2 + ni] = __builtin_amdgcn_mfma_f32_16x16x32_bf16(
                    aQ[2 * mi + 1], bHi[2 * ni + 1], acc[mi][2 + ni], 0, 0, 0);
            }
        __builtin_amdgcn_s_setprio(0);
        __builtin_amdgcn_sched_barrier(0);
        __builtin_amdgcn_s_barrier();

        // ---- phase 3: read A mi4-7; stage Bh0(t+2); MFMA (m1,n1); bar
        // (B-half0 of buf[t] last read p2; end-of-p2 barrier separates)
#pragma unroll
        for (int mi = 0; mi < 4; ++mi) {
            aQ[2 * mi] = *(const bf16x8*)(Ab + aO0 + (mi + 4) * 1024);
            aQ[2 * mi + 1] = *(const bf16x8*)(Ab + aO1 + (mi + 4) * 1024);
        }
        if (t + 2 < nt) { STGB(0, 0, t + 2); STGB(0, 1, t + 2); }
        __builtin_amdgcn_s_setprio(1);
#pragma unroll
        for (int mi = 0; mi < 4; ++mi)
#pragma unroll
            for (int ni = 0; ni < 2; ++ni) {
                acc[4 + mi][2 + ni] = __builtin_amdgcn_mfma_f32_16x16x32_bf16(
                    aQ[2 * mi], bHi[2 * ni], acc[4 + mi][2 + ni], 0, 0, 0);
                acc[4 + mi][2 + ni] = __builtin_amdgcn_mfma_f32_16x16x32_bf16(
                    aQ[2 * mi + 1], bHi[2 * ni + 1], acc[4 + mi][2 + ni], 0, 0, 0);
            }
        __builtin_amdgcn_s_setprio(0);
        __builtin_amdgcn_sched_barrier(0);
        __builtin_amdgcn_s_barrier();

        // ---- phase 4: stage Bh1(t+2); MFMA (m1,n0); vmcnt(4); bar
        if (t + 2 < nt) { STGB(1, 0, t + 2); STGB(1, 1, t + 2); }
        __builtin_amdgcn_s_setprio(1);
#pragma unroll
        for (int mi = 0; mi < 4; ++mi)
#pragma unroll
            for (int ni = 0; ni < 2; ++ni) {
                acc[4 + mi][ni] = __builtin_amdgcn_mfma_f32_16x16x32_bf16(
                    aQ[2 * mi], bLo[2 * ni], acc[4 + mi][ni], 0, 0, 0);
                acc[4 + mi][ni] = __builtin_amdgcn_mfma_f32_16x16x32_bf16(
                    aQ[2 * mi + 1], bLo[2 * ni + 1], acc[4 + mi][ni], 0, 0, 0);
            }
        __builtin_amdgcn_s_setprio(0);
        __builtin_amdgcn_sched_barrier(0);
        if (t < nt - 2) {
            asm volatile("s_waitcnt vmcnt(4)" ::: "memory");  // tile t+1 resident
        } else {
            asm volatile("s_waitcnt vmcnt(0)" ::: "memory");
        }
        __builtin_amdgcn_sched_barrier(0);
        __builtin_amdgcn_s_barrier();
    }

    // epilogue: C/D layout col = lane&15, row = (lane>>4)*4 + r  [m89]
    const int rowoff = (lane >> 4) * 4;
#pragma unroll
    for (int ni = 0; ni < 4; ++ni) {
        int gc = colBase + wc * 64 + ni * 16 + fr;
        float bv = bias[gc];
#pragma unroll
        for (int mi = 0; mi < 8; ++mi) {
            int gr = rowBase + wr * 128 + mi * 16 + rowoff;
#pragma unroll
            for (int r = 0; r < 4; ++r)
                C[(size_t)(gr + r) * N + gc] = acc[mi][ni][r] + bv;
        }
    }
}

// Fallback (no ws): f32 inputs, convert during staging (padded LDS, reg-staged).
__global__ __launch_bounds__(256) void k_gemm_f32(const float* __restrict__ Av,
                                                  const float* __restrict__ Bv,
                                                  const float* __restrict__ bias,
                                                  float* __restrict__ C,
                                                  int M, int N, int K) {
    __shared__ unsigned short sA[128 * 40];
    __shared__ unsigned short sB[128 * 40];

    const int nbn = N / 128;
    const int nwg = gridDim.x;
    int lin = blockIdx.x;
    int swz = lin;
    if ((nwg & 7) == 0) {
        int cpx = nwg >> 3;
        swz = (lin & 7) * cpx + (lin >> 3);
    }
    const int bm = swz / nbn, bn = swz % nbn;
    const int rowBase = bm * 128, colBase = bn * 128;

    const int tid = threadIdx.x;
    const int lane = tid & 63, wave = tid >> 6;
    const int wr = wave >> 1, wc = wave & 1;
    const int fr = lane & 15;
    const int kblk = (lane >> 4) * 8;

    f32x4 acc[4][4];
#pragma unroll
    for (int i = 0; i < 4; ++i)
#pragma unroll
        for (int j = 0; j < 4; ++j) acc[i][j] = (f32x4){0.f, 0.f, 0.f, 0.f};

    const int nk = K / 32;
    for (int kt = 0; kt < nk; ++kt) {
        const int kb = kt * 32;
        __syncthreads();
#pragma unroll
        for (int cc = 0; cc < 2; ++cc) {
            int c = tid + cc * 256;
            int row = c >> 2;
            int k8 = (c & 3) * 8;
            const float* gA = Av + (size_t)(rowBase + row) * K + kb + k8;
            const float* gB = Bv + (size_t)(colBase + row) * K + kb + k8;
            f32x4 a0 = *(const f32x4*)gA, a1 = *(const f32x4*)(gA + 4);
            f32x4 b0 = *(const f32x4*)gB, b1 = *(const f32x4*)(gB + 4);
            u16x8 va, vb;
#pragma unroll
            for (int j = 0; j < 4; ++j) {
                va[j] = f2bf(a0[j]); va[4 + j] = f2bf(a1[j]);
                vb[j] = f2bf(b0[j]); vb[4 + j] = f2bf(b1[j]);
            }
            *(u16x8*)&sA[row * 40 + k8] = va;
            *(u16x8*)&sB[row * 40 + k8] = vb;
        }
        __syncthreads();

        bf16x8 af[4], bfrag[4];
#pragma unroll
        for (int mi = 0; mi < 4; ++mi)
            af[mi] = *(const bf16x8*)&sA[(wr * 64 + mi * 16 + fr) * 40 + kblk];
#pragma unroll
        for (int ni = 0; ni < 4; ++ni)
            bfrag[ni] = *(const bf16x8*)&sB[(wc * 64 + ni * 16 + fr) * 40 + kblk];
#pragma unroll
        for (int mi = 0; mi < 4; ++mi)
#pragma unroll
            for (int ni = 0; ni < 4; ++ni)
                acc[mi][ni] = __builtin_amdgcn_mfma_f32_16x16x32_bf16(
                    af[mi], bfrag[ni], acc[mi][ni], 0, 0, 0);
    }

    const int rowoff = (lane >> 4) * 4;
#pragma unroll
    for (int ni = 0; ni < 4; ++ni) {
        int gc = colBase + wc * 64 + ni * 16 + fr;
        float bv = bias[gc];
#pragma unroll
        for (int mi = 0; mi < 4; ++mi) {
            int gr = rowBase + wr * 64 + mi * 16 + rowoff;
#pragma unroll
            for (int r = 0; r < 4; ++r)
                C[(size_t)(gr + r) * N + gc] = acc[mi][ni][r] + bv;
        }
    }
}

// Per-token outlier-aware fake-quant, in place. One block per row of D=2048.
__global__ __launch_bounds__(256) void k_quant(float* __restrict__ y, int D) {
    float* p = y + (size_t)blockIdx.x * D;
    const int tid = threadIdx.x;
    f32x4 v0 = *(const f32x4*)(p + tid * 8);
    f32x4 v1 = *(const f32x4*)(p + tid * 8 + 4);

    float s = 0.f, ss = 0.f;
#pragma unroll
    for (int j = 0; j < 4; ++j) {
        s += v0[j] + v1[j];
        ss += v0[j] * v0[j] + v1[j] * v1[j];
    }
#pragma unroll
    for (int off = 32; off > 0; off >>= 1) {
        s += __shfl_down(s, off, 64);
        ss += __shfl_down(ss, off, 64);
    }

    __shared__ float rs[4], rss[4], bc[2];
    const int wave = tid >> 6, lane = tid & 63;
    if (lane == 0) { rs[wave] = s; rss[wave] = ss; }
    __syncthreads();
    if (tid == 0) {
        float S = rs[0] + rs[1] + rs[2] + rs[3];
        float SS = rss[0] + rss[1] + rss[2] + rss[3];
        float mean = S / (float)D;
        float var = fmaxf(SS / (float)D - mean * mean, 0.f);
        bc[0] = THR_SIG * sqrtf(var);
    }
    __syncthreads();
    const float thr = bc[0];

    float m = 0.f;
#pragma unroll
    for (int j = 0; j < 4; ++j) {
        m = fmaxf(m, fminf(fabsf(v0[j]), thr));
        m = fmaxf(m, fminf(fabsf(v1[j]), thr));
    }
#pragma unroll
    for (int off = 32; off > 0; off >>= 1) m = fmaxf(m, __shfl_down(m, off, 64));
    if (lane == 0) rs[wave] = m;
    __syncthreads();
    if (tid == 0) {
        float mm = fmaxf(fmaxf(rs[0], rs[1]), fmaxf(rs[2], rs[3]));
        bc[1] = fmaxf(mm / QMAX_F, EPS_F);
    }
    __syncthreads();
    const float scale = bc[1];

#pragma unroll
    for (int j = 0; j < 4; ++j) {
        {
            float v = v0[j];
            float c = fminf(fmaxf(v, -thr), thr);
            float q = rintf(c / scale) * scale;
            v0[j] = (fabsf(v) > thr) ? v : q;
        }
        {
            float v = v1[j];
            float c = fminf(fmaxf(v, -thr), thr);
            float q = rintf(c / scale) * scale;
            v1[j] = (fabsf(v) > thr) ? v : q;
        }
    }
    *(f32x4*)(p + tid * 8) = v0;
    *(f32x4*)(p + tid * 8 + 4) = v1;
}

extern "C" void kernel_launch(void* const* d_in, const int* in_sizes, int n_in,
                              void* d_out, int out_size, void* d_ws, size_t ws_size,
                              hipStream_t stream) {
    const float* x = (const float*)d_in[0];
    const float* W = (const float*)d_in[1];
    const float* b = (const float*)d_in[2];
    float* out = (float*)d_out;

    const int Dout = in_sizes[2];
    const int Din = in_sizes[1] / Dout;
    const int M = in_sizes[0] / Din;

    const size_t nA = (size_t)M * Din;
    const size_t nB = (size_t)Dout * Din;
    const size_t need = (nA + nB) * sizeof(unsigned short);
    const bool fits8 = (M % 256 == 0) && (Dout % 256 == 0) && (Din % 64 == 0) && (Din >= 256);
    const bool pre = (ws_size >= need) && fits8;

    if (pre) {
        unsigned short* xb = (unsigned short*)d_ws;
        unsigned short* wb = xb + nA;
        int gA = (int)((nA + 8 * 256 - 1) / (8 * 256));
        int gB = (int)((nB + 8 * 256 - 1) / (8 * 256));
        k_convert<<<gA, 256, 0, stream>>>(x, xb, (long long)nA);
        k_convert<<<gB, 256, 0, stream>>>(W, wb, (long long)nB);
        int gridGemm = (M / 256) * (Dout / 256);
        k_gemm8<<<gridGemm, 512, 0, stream>>>(xb, wb, b, out, M, Dout, Din);
    } else {
        int gridGemm = (M / 128) * (Dout / 128);
        k_gemm_f32<<<gridGemm, 256, 0, stream>>>(x, W, b, out, M, Dout, Din);
    }
    k_quant<<<M, 256, 0, stream>>>(out, Dout);
}